// Round 2
// baseline (10067.870 us; speedup 1.0000x reference)
//
#include <hip/hip_runtime.h>
#include <hip/hip_bf16.h>
#include <math.h>

#define BLK 256

__device__ __forceinline__ float ldf(const float* p) { return *p; }
__device__ __forceinline__ float ldf(const __hip_bfloat16* p) { return __bfloat162float(*p); }
__device__ __forceinline__ void stf(float* p, float v) { *p = v; }
__device__ __forceinline__ void stf(__hip_bfloat16* p, float v) { *p = __float2bfloat16(v); }

// ---------------- fused conv3x3 + (BN) + activation ----------------
// ACT: 0 = none, 1 = leaky_relu(0.1), 2 = sigmoid
template<int CIN, int STRIDE, int ACT, bool HAS_BN, typename TIN, typename TOUT>
__global__ __launch_bounds__(BLK)
void conv3x3_k(const TIN* __restrict__ in, const float* __restrict__ w,
               const float* __restrict__ bconv,
               const float* __restrict__ bg, const float* __restrict__ bb,
               const float* __restrict__ bm, const float* __restrict__ bv,
               TOUT* __restrict__ out,
               int N, int COUT, int Hi, int Wi, int Ho, int Wo)
{
    int idx = blockIdx.x * BLK + threadIdx.x;
    int total = N * COUT * Ho * Wo;
    if (idx >= total) return;
    int x  = idx % Wo;
    int t1 = idx / Wo;
    int y  = t1 % Ho;
    int t2 = t1 / Ho;
    int co = t2 % COUT;
    int n  = t2 / COUT;

    const float* wp = w + (size_t)co * (CIN * 9);
    const TIN* ip = in + (size_t)n * CIN * Hi * Wi;
    int iy0 = y * STRIDE - 1;
    int ix0 = x * STRIDE - 1;
    float acc = 0.f;
    for (int ci = 0; ci < CIN; ++ci) {
        const TIN* ipc = ip + (size_t)ci * (Hi * Wi);
        const float* wc = wp + ci * 9;
        #pragma unroll
        for (int ky = 0; ky < 3; ++ky) {
            int iy = iy0 + ky;
            if ((unsigned)iy >= (unsigned)Hi) continue;
            const TIN* row = ipc + (size_t)iy * Wi;
            #pragma unroll
            for (int kx = 0; kx < 3; ++kx) {
                int ix = ix0 + kx;
                if ((unsigned)ix >= (unsigned)Wi) continue;
                acc = fmaf(ldf(row + ix), wc[ky * 3 + kx], acc);
            }
        }
    }
    float r;
    if (HAS_BN) {
        float s = bg[co] * rsqrtf(bv[co] + 1e-5f);
        r = acc * s + ((bconv[co] - bm[co]) * s + bb[co]);
    } else {
        r = acc + bconv[co];
    }
    if (ACT == 1) r = (r >= 0.f) ? r : 0.1f * r;
    if (ACT == 2) r = 1.f / (1.f + __expf(-r));
    stf(out + idx, r);
}

// ---------------- fused deconv3x3 (stride2, pad1, outpad1) + BN + lrelu ----------------
// weight layout: [CIN][COUT][3][3]
template<int CIN, typename TIN, typename TOUT>
__global__ __launch_bounds__(BLK)
void deconv3x3_k(const TIN* __restrict__ in, const float* __restrict__ w,
                 const float* __restrict__ bconv,
                 const float* __restrict__ bg, const float* __restrict__ bb,
                 const float* __restrict__ bm, const float* __restrict__ bv,
                 TOUT* __restrict__ out,
                 int N, int COUT, int Hi, int Wi)
{
    int Ho = Hi * 2, Wo = Wi * 2;
    int idx = blockIdx.x * BLK + threadIdx.x;
    int total = N * COUT * Ho * Wo;
    if (idx >= total) return;
    int x  = idx % Wo;
    int t1 = idx / Wo;
    int y  = t1 % Ho;
    int t2 = t1 / Ho;
    int co = t2 % COUT;
    int n  = t2 / COUT;

    const TIN* ip = in + (size_t)n * CIN * Hi * Wi;
    float acc = 0.f;
    for (int ci = 0; ci < CIN; ++ci) {
        const TIN* ipc = ip + (size_t)ci * (Hi * Wi);
        const float* wc = w + ((size_t)ci * COUT + co) * 9;
        #pragma unroll
        for (int ky = 0; ky < 3; ++ky) {
            int ty = y + 1 - ky;
            if (ty & 1) continue;
            int iy = ty >> 1;
            if ((unsigned)iy >= (unsigned)Hi) continue;
            const TIN* row = ipc + (size_t)iy * Wi;
            #pragma unroll
            for (int kx = 0; kx < 3; ++kx) {
                int tx = x + 1 - kx;
                if (tx & 1) continue;
                int ix = tx >> 1;
                if ((unsigned)ix >= (unsigned)Wi) continue;
                acc = fmaf(ldf(row + ix), wc[ky * 3 + kx], acc);
            }
        }
    }
    float s = bg[co] * rsqrtf(bv[co] + 1e-5f);
    float r = acc * s + ((bconv[co] - bm[co]) * s + bb[co]);
    r = (r >= 0.f) ? r : 0.1f * r;
    stf(out + idx, r);
}

// ---------------- VQ: nearest-embedding + q write + SSE + histogram ----------------
__global__ __launch_bounds__(256)
void vq_k(const float* __restrict__ z, const float* __restrict__ emb,
          float* __restrict__ q, float* __restrict__ sse_acc,
          unsigned int* __restrict__ counts, int HW, int CHW)
{
    __shared__ float se[256 * 10];
    __shared__ unsigned int hist[256];
    __shared__ float wsum[4];
    int tid = threadIdx.x;
    for (int i = tid; i < 2560; i += 256) se[i] = emb[i];
    hist[tid] = 0u;
    __syncthreads();

    int pos = blockIdx.x * 256 + tid;
    int b = pos / HW;
    int sp = pos - b * HW;
    const float* zp = z + (size_t)b * CHW + sp;
    float zv[10];
    #pragma unroll
    for (int c = 0; c < 10; ++c) zv[c] = zp[(size_t)c * HW];

    float best = 3.4e38f;
    int bi = 0;
    for (int k = 0; k < 256; ++k) {
        const float* e = se + k * 10;
        float d = 0.f;
        #pragma unroll
        for (int c = 0; c < 10; ++c) { float t = zv[c] - e[c]; d = fmaf(t, t, d); }
        if (d < best) { best = d; bi = k; }
    }
    atomicAdd(&hist[bi], 1u);

    float* qp = q + (size_t)b * CHW + sp;
    float lsse = 0.f;
    #pragma unroll
    for (int c = 0; c < 10; ++c) {
        float e = se[bi * 10 + c];
        qp[(size_t)c * HW] = e;
        float t = e - zv[c];
        lsse = fmaf(t, t, lsse);
    }
    #pragma unroll
    for (int off = 32; off > 0; off >>= 1) lsse += __shfl_down(lsse, off, 64);
    if ((tid & 63) == 0) wsum[tid >> 6] = lsse;
    __syncthreads();
    if (tid == 0) atomicAdd(sse_acc, wsum[0] + wsum[1] + wsum[2] + wsum[3]);
    atomicAdd(&counts[tid], hist[tid]);
}

__global__ __launch_bounds__(256)
void vq_finalize_k(const float* __restrict__ sse_acc, const unsigned int* __restrict__ counts,
                   float* __restrict__ out_loss, float* __restrict__ out_ppl,
                   float invNC, float invN)
{
    __shared__ float w4[4];
    int tid = threadIdx.x;
    float p = (float)counts[tid] * invN;
    float t = p * logf(p + 1e-10f);
    #pragma unroll
    for (int off = 32; off > 0; off >>= 1) t += __shfl_down(t, off, 64);
    if ((tid & 63) == 0) w4[tid >> 6] = t;
    __syncthreads();
    if (tid == 0) {
        float s = w4[0] + w4[1] + w4[2] + w4[3];
        *out_ppl  = expf(-s);
        *out_loss = 1.25f * sse_acc[0] * invNC;
    }
}

__global__ void zero_k(float* p, int n) {
    int i = blockIdx.x * 256 + threadIdx.x;
    if (i < n) p[i] = 0.f;
}

extern "C" void kernel_launch(void* const* d_in, const int* in_sizes, int n_in,
                              void* d_out, int out_size, void* d_ws, size_t ws_size,
                              hipStream_t stream) {
    const float* x      = (const float*)d_in[0];
    const float* enc_w1 = (const float*)d_in[1];
    const float* enc_b1 = (const float*)d_in[2];
    const float* bn1_g  = (const float*)d_in[3];
    const float* bn1_b  = (const float*)d_in[4];
    const float* bn1_m  = (const float*)d_in[5];
    const float* bn1_v  = (const float*)d_in[6];
    const float* enc_w2 = (const float*)d_in[7];
    const float* enc_b2 = (const float*)d_in[8];
    const float* bn2_g  = (const float*)d_in[9];
    const float* bn2_b  = (const float*)d_in[10];
    const float* bn2_m  = (const float*)d_in[11];
    const float* bn2_v  = (const float*)d_in[12];
    const float* enc_w3 = (const float*)d_in[13];
    const float* enc_b3 = (const float*)d_in[14];
    const float* bn3_g  = (const float*)d_in[15];
    const float* bn3_b  = (const float*)d_in[16];
    const float* bn3_m  = (const float*)d_in[17];
    const float* bn3_v  = (const float*)d_in[18];
    const float* emb    = (const float*)d_in[19];
    const float* dec_w1 = (const float*)d_in[20];
    const float* dec_b1 = (const float*)d_in[21];
    const float* dbn1_g = (const float*)d_in[22];
    const float* dbn1_b = (const float*)d_in[23];
    const float* dbn1_m = (const float*)d_in[24];
    const float* dbn1_v = (const float*)d_in[25];
    const float* dec_w2 = (const float*)d_in[26];
    const float* dec_b2 = (const float*)d_in[27];
    const float* dbn2_g = (const float*)d_in[28];
    const float* dbn2_b = (const float*)d_in[29];
    const float* dbn2_m = (const float*)d_in[30];
    const float* dbn2_v = (const float*)d_in[31];
    const float* dec_w3 = (const float*)d_in[32];
    const float* dec_b3 = (const float*)d_in[33];

    float* ws = (float*)d_ws;
    // workspace layout (float units)
    const size_t Z_OFF   = 0;                         // 1,310,720 f
    const size_t Q_OFF   = 1310720;                   // 1,310,720 f
    const size_t SSE_OFF = 2621440;                   // 1 f
    const size_t CNT_OFF = 2621441;                   // 256 u32
    const size_t RX_OFF  = 2621952;                   // h1 (fp32 16,777,216 f) then dd1 (bf16 33,554,432 = same bytes)
    const size_t RY_OFF  = RX_OFF + 16777216;         // h2 (fp32 8,388,608 f) then dd2 (bf16 67,108,864 = 33,554,432 f)
    const size_t NEEDED_F = RY_OFF + 33554432;        // 52,953,600 floats = 211.8 MB

    if (ws_size < NEEDED_F * sizeof(float)) return;   // deterministic guard (same every call)

    float* zbuf = ws + Z_OFF;
    float* qbuf = ws + Q_OFF;
    float* sse  = ws + SSE_OFF;
    unsigned int* counts = (unsigned int*)(ws + CNT_OFF);
    float* h1 = ws + RX_OFF;
    float* h2 = ws + RY_OFF;
    __hip_bfloat16* dd1 = (__hip_bfloat16*)(ws + RX_OFF);
    __hip_bfloat16* dd2 = (__hip_bfloat16*)(ws + RY_OFF);
    float* out = (float*)d_out;

    zero_k<<<2, 256, 0, stream>>>(ws + SSE_OFF, 257);

    // encoder (fp32 throughout to keep VQ argmin faithful)
    conv3x3_k<3, 2, 1, true><<<(32 * 32 * 128 * 128) / BLK, BLK, 0, stream>>>(
        x, enc_w1, enc_b1, bn1_g, bn1_b, bn1_m, bn1_v, h1, 32, 32, 256, 256, 128, 128);
    conv3x3_k<32, 2, 1, true><<<(32 * 64 * 64 * 64) / BLK, BLK, 0, stream>>>(
        h1, enc_w2, enc_b2, bn2_g, bn2_b, bn2_m, bn2_v, h2, 32, 64, 128, 128, 64, 64);
    conv3x3_k<64, 1, 0, true><<<(32 * 10 * 64 * 64) / BLK, BLK, 0, stream>>>(
        h2, enc_w3, enc_b3, bn3_g, bn3_b, bn3_m, bn3_v, zbuf, 32, 10, 64, 64, 64, 64);

    // vector quantization (fp32)
    vq_k<<<131072 / 256, 256, 0, stream>>>(zbuf, emb, qbuf, sse, counts, 4096, 40960);

    // decoder (bf16 intermediates)
    deconv3x3_k<10><<<(32 * 64 * 128 * 128) / BLK, BLK, 0, stream>>>(
        qbuf, dec_w1, dec_b1, dbn1_g, dbn1_b, dbn1_m, dbn1_v, dd1, 32, 64, 64, 64);
    deconv3x3_k<64><<<(32 * 32 * 256 * 256) / BLK, BLK, 0, stream>>>(
        dd1, dec_w2, dec_b2, dbn2_g, dbn2_b, dbn2_m, dbn2_v, dd2, 32, 32, 128, 128);
    conv3x3_k<32, 1, 2, false><<<(32 * 3 * 256 * 256) / BLK, BLK, 0, stream>>>(
        dd2, dec_w3, dec_b3, nullptr, nullptr, nullptr, nullptr, out, 32, 3, 256, 256, 256, 256);

    // scalars: loss at out[6291456], perplexity at out[6291457]
    vq_finalize_k<<<1, 256, 0, stream>>>(sse, counts, out + 6291456, out + 6291457,
                                         1.f / 1310720.f, 1.f / 131072.f);
}

// Round 3
// 1758.866 us; speedup vs baseline: 5.7241x; 5.7241x over previous
//
#include <hip/hip_runtime.h>
#include <hip/hip_bf16.h>
#include <math.h>

__device__ __forceinline__ float ldf(const float* p) { return *p; }
__device__ __forceinline__ float ldf(const __hip_bfloat16* p) { return __bfloat162float(*p); }
__device__ __forceinline__ void stf(float* p, float v) { *p = v; }
__device__ __forceinline__ void stf(__hip_bfloat16* p, float v) { *p = __float2bfloat16(v); }
__device__ __forceinline__ void st2(float* p, float a, float b) {
    float2 t; t.x = a; t.y = b; *(float2*)p = t;
}
__device__ __forceinline__ void st2(__hip_bfloat16* p, float a, float b) {
    __hip_bfloat162 t; t.x = __float2bfloat16(a); t.y = __float2bfloat16(b);
    *(__hip_bfloat162*)p = t;
}

__device__ __forceinline__ float actf(float r, int ACT) {
    if (ACT == 1) r = (r >= 0.f) ? r : 0.1f * r;
    if (ACT == 2) r = 1.f / (1.f + __expf(-r));
    return r;
}

// ================= register-tiled conv3x3 + BN + act =================
// weights [COUT][CIN][3][3]; thread: X_T outputs in x, CO_T channels.
// block: 64 threads in x, 4 in y. LDS weights: [CIN][CO_T][12] (pad->float4).
template<int CIN, int STRIDE, int X_T, int CO_T, int ACT, bool HAS_BN, typename TIN, typename TOUT>
__global__ __launch_bounds__(256)
void conv_t_k(const TIN* __restrict__ in, const float* __restrict__ w,
              const float* __restrict__ bconv,
              const float* __restrict__ bg, const float* __restrict__ bb,
              const float* __restrict__ bm, const float* __restrict__ bv,
              TOUT* __restrict__ out,
              int COUT, int Hi, int Wi, int Ho, int Wo,
              int cogs, int ytiles, int xtiles)
{
    constexpr int IC = (X_T - 1) * STRIDE + 3;
    __shared__ float sw[CIN * CO_T * 12];
    int b  = blockIdx.x;
    int xt = b % xtiles; b /= xtiles;
    int yt = b % ytiles; b /= ytiles;
    int cg = b % cogs;
    int n  = b / cogs;
    int co0 = cg * CO_T;
    int tid = threadIdx.x;
    for (int idx = tid; idx < CIN * CO_T * 9; idx += 256) {
        int t = idx % 9; int rest = idx / 9;
        int cot = rest % CO_T; int ci = rest / CO_T;
        sw[(ci * CO_T + cot) * 12 + t] = w[((size_t)(co0 + cot) * CIN + ci) * 9 + t];
    }
    __syncthreads();

    int tx = tid & 63, ty = tid >> 6;
    int y  = yt * 4 + ty;
    int x0 = (xt * 64 + tx) * X_T;
    int iyb = y * STRIDE - 1;
    int ixb = x0 * STRIDE - 1;
    const TIN* ip = in + (size_t)n * CIN * Hi * Wi;

    float acc[CO_T][X_T];
    #pragma unroll
    for (int c = 0; c < CO_T; ++c)
        #pragma unroll
        for (int u = 0; u < X_T; ++u) acc[c][u] = 0.f;

    for (int ci = 0; ci < CIN; ++ci) {
        const TIN* ipc = ip + (size_t)ci * Hi * Wi;
        float iv[3][IC];
        #pragma unroll
        for (int r = 0; r < 3; ++r) {
            int iy = iyb + r;
            bool vy = (unsigned)iy < (unsigned)Hi;
            const TIN* row = ipc + (size_t)iy * Wi;
            #pragma unroll
            for (int c = 0; c < IC; ++c) {
                int ix = ixb + c;
                iv[r][c] = (vy && (unsigned)ix < (unsigned)Wi) ? ldf(row + ix) : 0.f;
            }
        }
        #pragma unroll
        for (int cot = 0; cot < CO_T; ++cot) {
            const float4* wp4 = reinterpret_cast<const float4*>(&sw[(ci * CO_T + cot) * 12]);
            float4 wa = wp4[0], wb = wp4[1], wc4 = wp4[2];
            float wreg[12] = {wa.x, wa.y, wa.z, wa.w, wb.x, wb.y, wb.z, wb.w,
                              wc4.x, wc4.y, wc4.z, wc4.w};
            #pragma unroll
            for (int r = 0; r < 3; ++r)
                #pragma unroll
                for (int c = 0; c < 3; ++c)
                    #pragma unroll
                    for (int u = 0; u < X_T; ++u)
                        acc[cot][u] = fmaf(iv[r][u * STRIDE + c], wreg[r * 3 + c], acc[cot][u]);
        }
    }

    #pragma unroll
    for (int cot = 0; cot < CO_T; ++cot) {
        int co = co0 + cot;
        float s, bias;
        if (HAS_BN) {
            s = bg[co] * rsqrtf(bv[co] + 1e-5f);
            bias = (bconv[co] - bm[co]) * s + bb[co];
        } else { s = 1.f; bias = bconv[co]; }
        TOUT* op = out + (((size_t)n * COUT + co) * Ho + y) * Wo + x0;
        #pragma unroll
        for (int u = 0; u < X_T; ++u)
            stf(op + u, actf(acc[cot][u] * s + bias, ACT));
    }
}

// ============ phase-decomposed deconv3x3 (s2,p1,op1) + BN + lrelu ============
// weights [CIN][COUT][3][3]. Thread: input pos (i,j) -> 2x2 outputs x CO_T co.
template<int CIN, int CO_T, typename TIN, typename TOUT>
__global__ __launch_bounds__(256)
void deconv_t_k(const TIN* __restrict__ in, const float* __restrict__ w,
                const float* __restrict__ bconv,
                const float* __restrict__ bg, const float* __restrict__ bb,
                const float* __restrict__ bm, const float* __restrict__ bv,
                TOUT* __restrict__ out,
                int COUT, int Hi, int Wi, int cogs, int itiles, int jtiles)
{
    __shared__ float sw[CIN * CO_T * 12];
    int b  = blockIdx.x;
    int jt = b % jtiles; b /= jtiles;
    int it = b % itiles; b /= itiles;
    int cg = b % cogs;
    int n  = b / cogs;
    int co0 = cg * CO_T;
    int tid = threadIdx.x;
    for (int idx = tid; idx < CIN * CO_T * 9; idx += 256) {
        int t = idx % 9; int rest = idx / 9;
        int cot = rest % CO_T; int ci = rest / CO_T;
        sw[(ci * CO_T + cot) * 12 + t] = w[((size_t)ci * COUT + co0 + cot) * 9 + t];
    }
    __syncthreads();

    int tj = tid & 63, ti = tid >> 6;
    int i = it * 4 + ti;
    int j = jt * 64 + tj;
    bool vi = (i + 1) < Hi;
    bool vj = (j + 1) < Wi;
    const TIN* ip = in + (size_t)n * CIN * Hi * Wi + (size_t)i * Wi + j;

    float acc[CO_T][4];
    #pragma unroll
    for (int c = 0; c < CO_T; ++c)
        #pragma unroll
        for (int u = 0; u < 4; ++u) acc[c][u] = 0.f;

    for (int ci = 0; ci < CIN; ++ci) {
        const TIN* p = ip + (size_t)ci * Hi * Wi;
        float A = ldf(p);
        float B = vj ? ldf(p + 1) : 0.f;
        float C = vi ? ldf(p + Wi) : 0.f;
        float D = (vi && vj) ? ldf(p + Wi + 1) : 0.f;
        #pragma unroll
        for (int cot = 0; cot < CO_T; ++cot) {
            const float4* wp4 = reinterpret_cast<const float4*>(&sw[(ci * CO_T + cot) * 12]);
            float4 wa = wp4[0], wb = wp4[1], wc4 = wp4[2];
            float wreg[12] = {wa.x, wa.y, wa.z, wa.w, wb.x, wb.y, wb.z, wb.w,
                              wc4.x, wc4.y, wc4.z, wc4.w};
            // out(2i,2j)     = w11*A
            // out(2i,2j+1)   = w10*B + w12*A
            // out(2i+1,2j)   = w01*C + w21*A
            // out(2i+1,2j+1) = w00*D + w02*C + w20*B + w22*A
            acc[cot][0] = fmaf(wreg[4], A, acc[cot][0]);
            acc[cot][1] = fmaf(wreg[3], B, fmaf(wreg[5], A, acc[cot][1]));
            acc[cot][2] = fmaf(wreg[1], C, fmaf(wreg[7], A, acc[cot][2]));
            acc[cot][3] = fmaf(wreg[0], D, fmaf(wreg[2], C,
                          fmaf(wreg[6], B, fmaf(wreg[8], A, acc[cot][3]))));
        }
    }

    int Ho = Hi * 2, Wo = Wi * 2;
    #pragma unroll
    for (int cot = 0; cot < CO_T; ++cot) {
        int co = co0 + cot;
        float s = bg[co] * rsqrtf(bv[co] + 1e-5f);
        float bias = (bconv[co] - bm[co]) * s + bb[co];
        float r0 = actf(acc[cot][0] * s + bias, 1);
        float r1 = actf(acc[cot][1] * s + bias, 1);
        float r2 = actf(acc[cot][2] * s + bias, 1);
        float r3 = actf(acc[cot][3] * s + bias, 1);
        TOUT* op = out + (((size_t)n * COUT + co) * Ho + 2 * i) * Wo + 2 * j;
        st2(op, r0, r1);
        st2(op + Wo, r2, r3);
    }
}

// ---------------- VQ: nearest-embedding + q write + SSE + histogram ----------------
__global__ __launch_bounds__(256)
void vq_k(const float* __restrict__ z, const float* __restrict__ emb,
          float* __restrict__ q, float* __restrict__ sse_acc,
          unsigned int* __restrict__ counts, int HW, int CHW)
{
    __shared__ float se[256 * 10];
    __shared__ unsigned int hist[256];
    __shared__ float wsum[4];
    int tid = threadIdx.x;
    for (int i = tid; i < 2560; i += 256) se[i] = emb[i];
    hist[tid] = 0u;
    __syncthreads();

    int pos = blockIdx.x * 256 + tid;
    int b = pos / HW;
    int sp = pos - b * HW;
    const float* zp = z + (size_t)b * CHW + sp;
    float zv[10];
    #pragma unroll
    for (int c = 0; c < 10; ++c) zv[c] = zp[(size_t)c * HW];

    float best = 3.4e38f;
    int bi = 0;
    for (int k = 0; k < 256; ++k) {
        const float* e = se + k * 10;
        float d = 0.f;
        #pragma unroll
        for (int c = 0; c < 10; ++c) { float t = zv[c] - e[c]; d = fmaf(t, t, d); }
        if (d < best) { best = d; bi = k; }
    }
    atomicAdd(&hist[bi], 1u);

    float* qp = q + (size_t)b * CHW + sp;
    float lsse = 0.f;
    #pragma unroll
    for (int c = 0; c < 10; ++c) {
        float e = se[bi * 10 + c];
        qp[(size_t)c * HW] = e;
        float t = e - zv[c];
        lsse = fmaf(t, t, lsse);
    }
    #pragma unroll
    for (int off = 32; off > 0; off >>= 1) lsse += __shfl_down(lsse, off, 64);
    if ((tid & 63) == 0) wsum[tid >> 6] = lsse;
    __syncthreads();
    if (tid == 0) atomicAdd(sse_acc, wsum[0] + wsum[1] + wsum[2] + wsum[3]);
    atomicAdd(&counts[tid], hist[tid]);
}

__global__ __launch_bounds__(256)
void vq_finalize_k(const float* __restrict__ sse_acc, const unsigned int* __restrict__ counts,
                   float* __restrict__ out_loss, float* __restrict__ out_ppl,
                   float invNC, float invN)
{
    __shared__ float w4[4];
    int tid = threadIdx.x;
    float p = (float)counts[tid] * invN;
    float t = p * logf(p + 1e-10f);
    #pragma unroll
    for (int off = 32; off > 0; off >>= 1) t += __shfl_down(t, off, 64);
    if ((tid & 63) == 0) w4[tid >> 6] = t;
    __syncthreads();
    if (tid == 0) {
        float s = w4[0] + w4[1] + w4[2] + w4[3];
        *out_ppl  = expf(-s);
        *out_loss = 1.25f * sse_acc[0] * invNC;
    }
}

__global__ void zero_k(float* p, int n) {
    int i = blockIdx.x * 256 + threadIdx.x;
    if (i < n) p[i] = 0.f;
}

extern "C" void kernel_launch(void* const* d_in, const int* in_sizes, int n_in,
                              void* d_out, int out_size, void* d_ws, size_t ws_size,
                              hipStream_t stream) {
    const float* x      = (const float*)d_in[0];
    const float* enc_w1 = (const float*)d_in[1];
    const float* enc_b1 = (const float*)d_in[2];
    const float* bn1_g  = (const float*)d_in[3];
    const float* bn1_b  = (const float*)d_in[4];
    const float* bn1_m  = (const float*)d_in[5];
    const float* bn1_v  = (const float*)d_in[6];
    const float* enc_w2 = (const float*)d_in[7];
    const float* enc_b2 = (const float*)d_in[8];
    const float* bn2_g  = (const float*)d_in[9];
    const float* bn2_b  = (const float*)d_in[10];
    const float* bn2_m  = (const float*)d_in[11];
    const float* bn2_v  = (const float*)d_in[12];
    const float* enc_w3 = (const float*)d_in[13];
    const float* enc_b3 = (const float*)d_in[14];
    const float* bn3_g  = (const float*)d_in[15];
    const float* bn3_b  = (const float*)d_in[16];
    const float* bn3_m  = (const float*)d_in[17];
    const float* bn3_v  = (const float*)d_in[18];
    const float* emb    = (const float*)d_in[19];
    const float* dec_w1 = (const float*)d_in[20];
    const float* dec_b1 = (const float*)d_in[21];
    const float* dbn1_g = (const float*)d_in[22];
    const float* dbn1_b = (const float*)d_in[23];
    const float* dbn1_m = (const float*)d_in[24];
    const float* dbn1_v = (const float*)d_in[25];
    const float* dec_w2 = (const float*)d_in[26];
    const float* dec_b2 = (const float*)d_in[27];
    const float* dbn2_g = (const float*)d_in[28];
    const float* dbn2_b = (const float*)d_in[29];
    const float* dbn2_m = (const float*)d_in[30];
    const float* dbn2_v = (const float*)d_in[31];
    const float* dec_w3 = (const float*)d_in[32];
    const float* dec_b3 = (const float*)d_in[33];

    float* ws = (float*)d_ws;
    const size_t Z_OFF   = 0;                         // 1,310,720 f
    const size_t Q_OFF   = 1310720;                   // 1,310,720 f
    const size_t SSE_OFF = 2621440;                   // 1 f
    const size_t CNT_OFF = 2621441;                   // 256 u32
    const size_t RX_OFF  = 2621952;                   // h1 fp32 16,777,216 f | dd1 bf16 (same bytes)
    const size_t RY_OFF  = RX_OFF + 16777216;         // h2 fp32 8,388,608 f | dd2 bf16 33,554,432 f
    const size_t NEEDED_F = RY_OFF + 33554432;

    if (ws_size < NEEDED_F * sizeof(float)) return;

    float* zbuf = ws + Z_OFF;
    float* qbuf = ws + Q_OFF;
    float* sse  = ws + SSE_OFF;
    unsigned int* counts = (unsigned int*)(ws + CNT_OFF);
    float* h1 = ws + RX_OFF;
    float* h2 = ws + RY_OFF;
    __hip_bfloat16* dd1 = (__hip_bfloat16*)(ws + RX_OFF);
    __hip_bfloat16* dd2 = (__hip_bfloat16*)(ws + RY_OFF);
    float* out = (float*)d_out;

    zero_k<<<2, 256, 0, stream>>>(ws + SSE_OFF, 257);

    // conv1: 3->32, s2, 256->128. cogs=8(CO_T=4), ytiles=32, xtiles=2(X_T=1)
    conv_t_k<3, 2, 1, 4, 1, true><<<32 * 8 * 32 * 2, 256, 0, stream>>>(
        x, enc_w1, enc_b1, bn1_g, bn1_b, bn1_m, bn1_v, h1, 32, 256, 256, 128, 128, 8, 32, 2);
    // conv2: 32->64, s2, 128->64. cogs=16, ytiles=16, xtiles=1
    conv_t_k<32, 2, 1, 4, 1, true><<<32 * 16 * 16, 256, 0, stream>>>(
        h1, enc_w2, enc_b2, bn2_g, bn2_b, bn2_m, bn2_v, h2, 64, 128, 128, 64, 64, 16, 16, 1);
    // conv3: 64->10, s1, 64. CO_T=5, cogs=2, ytiles=16, xtiles=1
    conv_t_k<64, 1, 1, 5, 0, true><<<32 * 2 * 16, 256, 0, stream>>>(
        h2, enc_w3, enc_b3, bn3_g, bn3_b, bn3_m, bn3_v, zbuf, 10, 64, 64, 64, 64, 2, 16, 1);

    vq_k<<<131072 / 256, 256, 0, stream>>>(zbuf, emb, qbuf, sse, counts, 4096, 40960);

    // deconv1: 10->64, 64->128. CO_T=8, cogs=8, itiles=16, jtiles=1
    deconv_t_k<10, 8><<<32 * 8 * 16, 256, 0, stream>>>(
        qbuf, dec_w1, dec_b1, dbn1_g, dbn1_b, dbn1_m, dbn1_v, dd1, 64, 64, 64, 8, 16, 1);
    // deconv2: 64->32, 128->256. CO_T=4, cogs=8, itiles=32, jtiles=2
    deconv_t_k<64, 4><<<32 * 8 * 32 * 2, 256, 0, stream>>>(
        dd1, dec_w2, dec_b2, dbn2_g, dbn2_b, dbn2_m, dbn2_v, dd2, 32, 128, 128, 8, 32, 2);
    // conv_out: 32->3, s1, 256. CO_T=3, cogs=1, ytiles=64, xtiles=1 (X_T=4)
    conv_t_k<32, 1, 4, 3, 2, false><<<32 * 64, 256, 0, stream>>>(
        dd2, dec_w3, dec_b3, nullptr, nullptr, nullptr, nullptr, out, 3, 256, 256, 256, 256, 1, 64, 1);

    vq_finalize_k<<<1, 256, 0, stream>>>(sse, counts, out + 6291456, out + 6291457,
                                         1.f / 1310720.f, 1.f / 131072.f);
}

// Round 4
// 1612.440 us; speedup vs baseline: 6.2439x; 1.0908x over previous
//
#include <hip/hip_runtime.h>
#include <hip/hip_bf16.h>
#include <math.h>

__device__ __forceinline__ float ldf(const float* p) { return *p; }
__device__ __forceinline__ float ldf(const __hip_bfloat16* p) { return __bfloat162float(*p); }
__device__ __forceinline__ void ld2(const float* p, float& a, float& b) {
    float2 t = *(const float2*)p; a = t.x; b = t.y;
}
__device__ __forceinline__ void ld2(const __hip_bfloat16* p, float& a, float& b) {
    __hip_bfloat162 t = *(const __hip_bfloat162*)p;
    a = __bfloat162float(t.x); b = __bfloat162float(t.y);
}
__device__ __forceinline__ void stf(float* p, float v) { *p = v; }
__device__ __forceinline__ void stf(__hip_bfloat16* p, float v) { *p = __float2bfloat16(v); }
__device__ __forceinline__ void st4(float* p, float a, float b, float c, float d) {
    float4 t; t.x = a; t.y = b; t.z = c; t.w = d; *(float4*)p = t;
}
__device__ __forceinline__ void st4(__hip_bfloat16* p, float a, float b, float c, float d) {
    union { __hip_bfloat162 h[2]; float2 f; } u;
    u.h[0] = __halves2bfloat162(__float2bfloat16(a), __float2bfloat16(b));
    u.h[1] = __halves2bfloat162(__float2bfloat16(c), __float2bfloat16(d));
    *(float2*)p = u.f;
}

__device__ __forceinline__ float actf(float r, int ACT) {
    if (ACT == 1) r = (r >= 0.f) ? r : 0.1f * r;
    if (ACT == 2) r = 1.f / (1.f + __expf(-r));
    return r;
}

// ================= register-tiled conv3x3 + BN + act =================
// weights [COUT][CIN][3][3]; block: BX lanes in x (X_T outs each), 256/BX rows.
template<int CIN, int STRIDE, int BX, int X_T, int CO_T, int ACT, bool HAS_BN,
         typename TIN, typename TOUT>
__global__ __launch_bounds__(256)
void conv_t_k(const TIN* __restrict__ in, const float* __restrict__ w,
              const float* __restrict__ bconv,
              const float* __restrict__ bg, const float* __restrict__ bb,
              const float* __restrict__ bm, const float* __restrict__ bv,
              TOUT* __restrict__ out,
              int COUT, int Hi, int Wi, int Ho, int Wo,
              int cogs, int ytiles, int xtiles)
{
    constexpr int BY = 256 / BX;
    constexpr int IC = (X_T - 1) * STRIDE + 3;
    __shared__ float sw[CIN * CO_T * 12];
    int b  = blockIdx.x;
    int xt = b % xtiles; b /= xtiles;
    int yt = b % ytiles; b /= ytiles;
    int cg = b % cogs;
    int n  = b / cogs;
    int co0 = cg * CO_T;
    int tid = threadIdx.x;
    for (int idx = tid; idx < CIN * CO_T * 9; idx += 256) {
        int t = idx % 9; int rest = idx / 9;
        int cot = rest % CO_T; int ci = rest / CO_T;
        sw[(ci * CO_T + cot) * 12 + t] = w[((size_t)(co0 + cot) * CIN + ci) * 9 + t];
    }
    __syncthreads();

    int tx = tid % BX, ty = tid / BX;
    int y  = yt * BY + ty;
    int x0 = (xt * BX + tx) * X_T;
    int iyb = y * STRIDE - 1;
    int ixb = x0 * STRIDE - 1;
    const TIN* ip = in + (size_t)n * CIN * Hi * Wi;

    float acc[CO_T][X_T];
    #pragma unroll
    for (int c = 0; c < CO_T; ++c)
        #pragma unroll
        for (int u = 0; u < X_T; ++u) acc[c][u] = 0.f;

    for (int ci = 0; ci < CIN; ++ci) {
        const TIN* ipc = ip + (size_t)ci * Hi * Wi;
        float iv[3][IC];
        #pragma unroll
        for (int r = 0; r < 3; ++r) {
            int iy = iyb + r;
            bool vy = (unsigned)iy < (unsigned)Hi;
            const TIN* row = ipc + (size_t)iy * Wi;
            #pragma unroll
            for (int c = 0; c < IC; ++c) {
                int ix = ixb + c;
                iv[r][c] = (vy && (unsigned)ix < (unsigned)Wi) ? ldf(row + ix) : 0.f;
            }
        }
        #pragma unroll
        for (int cot = 0; cot < CO_T; ++cot) {
            const float4* wp4 = reinterpret_cast<const float4*>(&sw[(ci * CO_T + cot) * 12]);
            float4 wa = wp4[0], wb = wp4[1], wc4 = wp4[2];
            float wreg[12] = {wa.x, wa.y, wa.z, wa.w, wb.x, wb.y, wb.z, wb.w,
                              wc4.x, wc4.y, wc4.z, wc4.w};
            #pragma unroll
            for (int r = 0; r < 3; ++r)
                #pragma unroll
                for (int c = 0; c < 3; ++c)
                    #pragma unroll
                    for (int u = 0; u < X_T; ++u)
                        acc[cot][u] = fmaf(iv[r][u * STRIDE + c], wreg[r * 3 + c], acc[cot][u]);
        }
    }

    #pragma unroll
    for (int cot = 0; cot < CO_T; ++cot) {
        int co = co0 + cot;
        float s, bias;
        if (HAS_BN) {
            s = bg[co] * rsqrtf(bv[co] + 1e-5f);
            bias = (bconv[co] - bm[co]) * s + bb[co];
        } else { s = 1.f; bias = bconv[co]; }
        TOUT* op = out + (((size_t)n * COUT + co) * Ho + y) * Wo + x0;
        #pragma unroll
        for (int u = 0; u < X_T; ++u)
            stf(op + u, actf(acc[cot][u] * s + bias, ACT));
    }
}

// ====== phase-decomposed deconv3x3 (s2,p1,op1) + BN + lrelu, 2x2 pos/thread ======
// weights [CIN][COUT][3][3]. Thread: 2x2 input positions -> 4x4 outputs x CO_T.
// block: BJ lanes in j, 256/BJ in i. Requires BJ*2 == Wi (full-width j coverage).
template<int CIN, int CO_T, int BJ, typename TIN, typename TOUT>
__global__ __launch_bounds__(256)
void deconv_t2_k(const TIN* __restrict__ in, const float* __restrict__ w,
                 const float* __restrict__ bconv,
                 const float* __restrict__ bg, const float* __restrict__ bb,
                 const float* __restrict__ bm, const float* __restrict__ bv,
                 TOUT* __restrict__ out,
                 int COUT, int Hi, int Wi, int cogs, int itiles)
{
    constexpr int BI = 256 / BJ;
    __shared__ float sw[CIN * CO_T * 12];
    int b  = blockIdx.x;
    int it = b % itiles; b /= itiles;
    int cg = b % cogs;
    int n  = b / cogs;
    int co0 = cg * CO_T;
    int tid = threadIdx.x;
    for (int idx = tid; idx < CIN * CO_T * 9; idx += 256) {
        int t = idx % 9; int rest = idx / 9;
        int cot = rest % CO_T; int ci = rest / CO_T;
        sw[(ci * CO_T + cot) * 12 + t] = w[((size_t)ci * COUT + co0 + cot) * 9 + t];
    }
    __syncthreads();

    int tj = tid % BJ, ti = tid / BJ;
    int i0 = (it * BI + ti) * 2;
    int j0 = tj * 2;
    bool v_i2 = (i0 + 2) < Hi;
    bool v_j2 = (j0 + 2) < Wi;
    const TIN* ip = in + (size_t)n * CIN * Hi * Wi + (size_t)i0 * Wi + j0;

    float acc[CO_T][4][4];
    #pragma unroll
    for (int c = 0; c < CO_T; ++c)
        #pragma unroll
        for (int r = 0; r < 4; ++r)
            #pragma unroll
            for (int u = 0; u < 4; ++u) acc[c][r][u] = 0.f;

    for (int ci = 0; ci < CIN; ++ci) {
        const TIN* p = ip + (size_t)ci * Hi * Wi;
        float iv[3][3];
        #pragma unroll
        for (int r = 0; r < 3; ++r) {
            bool vr = (r < 2) || v_i2;
            const TIN* rp = p + (size_t)r * Wi;
            if (vr) {
                ld2(rp, iv[r][0], iv[r][1]);
                iv[r][2] = v_j2 ? ldf(rp + 2) : 0.f;
            } else {
                iv[r][0] = 0.f; iv[r][1] = 0.f; iv[r][2] = 0.f;
            }
        }
        #pragma unroll
        for (int cot = 0; cot < CO_T; ++cot) {
            const float4* wp4 = reinterpret_cast<const float4*>(&sw[(ci * CO_T + cot) * 12]);
            float4 wa = wp4[0], wb = wp4[1], wc4 = wp4[2];
            float w0 = wa.x, w1 = wa.y, w2 = wa.z, w3 = wa.w;
            float w4 = wb.x, w5 = wb.y, w6 = wb.z, w7 = wb.w, w8 = wc4.x;
            #pragma unroll
            for (int pi = 0; pi < 2; ++pi)
                #pragma unroll
                for (int pj = 0; pj < 2; ++pj) {
                    float A = iv[pi][pj],     B = iv[pi][pj + 1];
                    float C = iv[pi + 1][pj], D = iv[pi + 1][pj + 1];
                    acc[cot][2*pi  ][2*pj  ] = fmaf(w4, A, acc[cot][2*pi  ][2*pj  ]);
                    acc[cot][2*pi  ][2*pj+1] = fmaf(w3, B, fmaf(w5, A, acc[cot][2*pi  ][2*pj+1]));
                    acc[cot][2*pi+1][2*pj  ] = fmaf(w1, C, fmaf(w7, A, acc[cot][2*pi+1][2*pj  ]));
                    acc[cot][2*pi+1][2*pj+1] = fmaf(w0, D, fmaf(w2, C,
                                               fmaf(w6, B, fmaf(w8, A, acc[cot][2*pi+1][2*pj+1]))));
                }
        }
    }

    int Ho = Hi * 2, Wo = Wi * 2;
    #pragma unroll
    for (int cot = 0; cot < CO_T; ++cot) {
        int co = co0 + cot;
        float s = bg[co] * rsqrtf(bv[co] + 1e-5f);
        float bias = (bconv[co] - bm[co]) * s + bb[co];
        TOUT* op = out + (((size_t)n * COUT + co) * Ho + 2 * i0) * Wo + 2 * j0;
        #pragma unroll
        for (int rr = 0; rr < 4; ++rr) {
            st4(op + (size_t)rr * Wo,
                actf(acc[cot][rr][0] * s + bias, 1),
                actf(acc[cot][rr][1] * s + bias, 1),
                actf(acc[cot][rr][2] * s + bias, 1),
                actf(acc[cot][rr][3] * s + bias, 1));
        }
    }
}

// ---------------- VQ: nearest-embedding + q write + SSE + histogram ----------------
__global__ __launch_bounds__(256)
void vq_k(const float* __restrict__ z, const float* __restrict__ emb,
          float* __restrict__ q, float* __restrict__ sse_acc,
          unsigned int* __restrict__ counts, int HW, int CHW)
{
    __shared__ float se[256 * 10];
    __shared__ unsigned int hist[256];
    __shared__ float wsum[4];
    int tid = threadIdx.x;
    for (int i = tid; i < 2560; i += 256) se[i] = emb[i];
    hist[tid] = 0u;
    __syncthreads();

    int pos = blockIdx.x * 256 + tid;
    int b = pos / HW;
    int sp = pos - b * HW;
    const float* zp = z + (size_t)b * CHW + sp;
    float zv[10];
    #pragma unroll
    for (int c = 0; c < 10; ++c) zv[c] = zp[(size_t)c * HW];

    float best = 3.4e38f;
    int bi = 0;
    for (int k = 0; k < 256; ++k) {
        const float* e = se + k * 10;
        float d = 0.f;
        #pragma unroll
        for (int c = 0; c < 10; ++c) { float t = zv[c] - e[c]; d = fmaf(t, t, d); }
        if (d < best) { best = d; bi = k; }
    }
    atomicAdd(&hist[bi], 1u);

    float* qp = q + (size_t)b * CHW + sp;
    float lsse = 0.f;
    #pragma unroll
    for (int c = 0; c < 10; ++c) {
        float e = se[bi * 10 + c];
        qp[(size_t)c * HW] = e;
        float t = e - zv[c];
        lsse = fmaf(t, t, lsse);
    }
    #pragma unroll
    for (int off = 32; off > 0; off >>= 1) lsse += __shfl_down(lsse, off, 64);
    if ((tid & 63) == 0) wsum[tid >> 6] = lsse;
    __syncthreads();
    if (tid == 0) atomicAdd(sse_acc, wsum[0] + wsum[1] + wsum[2] + wsum[3]);
    atomicAdd(&counts[tid], hist[tid]);
}

__global__ __launch_bounds__(256)
void vq_finalize_k(const float* __restrict__ sse_acc, const unsigned int* __restrict__ counts,
                   float* __restrict__ out_loss, float* __restrict__ out_ppl,
                   float invNC, float invN)
{
    __shared__ float w4[4];
    int tid = threadIdx.x;
    float p = (float)counts[tid] * invN;
    float t = p * logf(p + 1e-10f);
    #pragma unroll
    for (int off = 32; off > 0; off >>= 1) t += __shfl_down(t, off, 64);
    if ((tid & 63) == 0) w4[tid >> 6] = t;
    __syncthreads();
    if (tid == 0) {
        float s = w4[0] + w4[1] + w4[2] + w4[3];
        *out_ppl  = expf(-s);
        *out_loss = 1.25f * sse_acc[0] * invNC;
    }
}

__global__ void zero_k(float* p, int n) {
    int i = blockIdx.x * 256 + threadIdx.x;
    if (i < n) p[i] = 0.f;
}

extern "C" void kernel_launch(void* const* d_in, const int* in_sizes, int n_in,
                              void* d_out, int out_size, void* d_ws, size_t ws_size,
                              hipStream_t stream) {
    const float* x      = (const float*)d_in[0];
    const float* enc_w1 = (const float*)d_in[1];
    const float* enc_b1 = (const float*)d_in[2];
    const float* bn1_g  = (const float*)d_in[3];
    const float* bn1_b  = (const float*)d_in[4];
    const float* bn1_m  = (const float*)d_in[5];
    const float* bn1_v  = (const float*)d_in[6];
    const float* enc_w2 = (const float*)d_in[7];
    const float* enc_b2 = (const float*)d_in[8];
    const float* bn2_g  = (const float*)d_in[9];
    const float* bn2_b  = (const float*)d_in[10];
    const float* bn2_m  = (const float*)d_in[11];
    const float* bn2_v  = (const float*)d_in[12];
    const float* enc_w3 = (const float*)d_in[13];
    const float* enc_b3 = (const float*)d_in[14];
    const float* bn3_g  = (const float*)d_in[15];
    const float* bn3_b  = (const float*)d_in[16];
    const float* bn3_m  = (const float*)d_in[17];
    const float* bn3_v  = (const float*)d_in[18];
    const float* emb    = (const float*)d_in[19];
    const float* dec_w1 = (const float*)d_in[20];
    const float* dec_b1 = (const float*)d_in[21];
    const float* dbn1_g = (const float*)d_in[22];
    const float* dbn1_b = (const float*)d_in[23];
    const float* dbn1_m = (const float*)d_in[24];
    const float* dbn1_v = (const float*)d_in[25];
    const float* dec_w2 = (const float*)d_in[26];
    const float* dec_b2 = (const float*)d_in[27];
    const float* dbn2_g = (const float*)d_in[28];
    const float* dbn2_b = (const float*)d_in[29];
    const float* dbn2_m = (const float*)d_in[30];
    const float* dbn2_v = (const float*)d_in[31];
    const float* dec_w3 = (const float*)d_in[32];
    const float* dec_b3 = (const float*)d_in[33];

    float* ws = (float*)d_ws;
    const size_t Z_OFF   = 0;                         // 1,310,720 f
    const size_t Q_OFF   = 1310720;                   // 1,310,720 f
    const size_t SSE_OFF = 2621440;                   // 1 f
    const size_t CNT_OFF = 2621441;                   // 256 u32
    const size_t RX_OFF  = 2621952;                   // h1 fp32 | dd1 bf16 (same bytes)
    const size_t RY_OFF  = RX_OFF + 16777216;         // h2 fp32 | dd2 bf16
    const size_t NEEDED_F = RY_OFF + 33554432;

    if (ws_size < NEEDED_F * sizeof(float)) return;

    float* zbuf = ws + Z_OFF;
    float* qbuf = ws + Q_OFF;
    float* sse  = ws + SSE_OFF;
    unsigned int* counts = (unsigned int*)(ws + CNT_OFF);
    float* h1 = ws + RX_OFF;
    float* h2 = ws + RY_OFF;
    __hip_bfloat16* dd1 = (__hip_bfloat16*)(ws + RX_OFF);
    __hip_bfloat16* dd2 = (__hip_bfloat16*)(ws + RY_OFF);
    float* out = (float*)d_out;

    zero_k<<<2, 256, 0, stream>>>(ws + SSE_OFF, 257);

    // conv1: 3->32, s2, 256->128. BX=64,X_T=2 (covers 128), CO_T=4, cogs=8, ytiles=32
    conv_t_k<3, 2, 64, 2, 4, 1, true><<<32 * 8 * 32, 256, 0, stream>>>(
        x, enc_w1, enc_b1, bn1_g, bn1_b, bn1_m, bn1_v, h1, 32, 256, 256, 128, 128, 8, 32, 1);
    // conv2: 32->64, s2, 128->64. BX=16,X_T=4 (covers 64), CO_T=4, cogs=16, ytiles=4 (BY=16)
    conv_t_k<32, 2, 16, 4, 4, 1, true><<<32 * 16 * 4, 256, 0, stream>>>(
        h1, enc_w2, enc_b2, bn2_g, bn2_b, bn2_m, bn2_v, h2, 64, 128, 128, 64, 64, 16, 4, 1);
    // conv3: 64->10, s1, 64. BX=32,X_T=2 (covers 64), CO_T=5, cogs=2, ytiles=8 (BY=8)
    conv_t_k<64, 1, 32, 2, 5, 0, true><<<32 * 2 * 8, 256, 0, stream>>>(
        h2, enc_w3, enc_b3, bn3_g, bn3_b, bn3_m, bn3_v, zbuf, 10, 64, 64, 64, 64, 2, 8, 1);

    vq_k<<<131072 / 256, 256, 0, stream>>>(zbuf, emb, qbuf, sse, counts, 4096, 40960);

    // deconv1: 10->64, 64->128. BJ=32 (j: 32*2=64), BI=8, itiles=4, CO_T=4, cogs=16
    deconv_t2_k<10, 4, 32><<<32 * 16 * 4, 256, 0, stream>>>(
        qbuf, dec_w1, dec_b1, dbn1_g, dbn1_b, dbn1_m, dbn1_v, dd1, 64, 64, 64, 16, 4);
    // deconv2: 64->32, 128->256. BJ=64 (j: 64*2=128), BI=4, itiles=16, CO_T=4, cogs=8
    deconv_t2_k<64, 4, 64><<<32 * 8 * 16, 256, 0, stream>>>(
        dd1, dec_w2, dec_b2, dbn2_g, dbn2_b, dbn2_m, dbn2_v, dd2, 32, 128, 128, 8, 16);
    // conv_out: 32->3, s1, 256. BX=64,X_T=4 (covers 256), CO_T=3, cogs=1, ytiles=64
    conv_t_k<32, 1, 64, 4, 3, 2, false><<<32 * 64, 256, 0, stream>>>(
        dd2, dec_w3, dec_b3, nullptr, nullptr, nullptr, nullptr, out, 3, 256, 256, 256, 256, 1, 64, 1);

    vq_finalize_k<<<1, 256, 0, stream>>>(sse, counts, out + 6291456, out + 6291457,
                                         1.f / 1310720.f, 1.f / 131072.f);
}